// Round 6
// baseline (1374.003 us; speedup 1.0000x reference)
//
#include <hip/hip_runtime.h>

#define HW 3136      // 56*56
#define SHS 120      // sH row stride: 112 px (2 rows x 56, contiguous) + 8 pad

// Fused residual-stage: grouped3x3 conv + bias + BN + ReLU -> (LDS) -> grouped1x1 conv
// + bias + BN + ReLU -> global.
// v6: phase 1 lanes = 8 k x 8 px-slots; two aligned float4 loads cover a full channel
// row with ZERO line redundancy (16 lines/inst vs v2's ~64 with 8x re-request).
// Halo via 2 shfl per (k,cc,ry) (16x fewer than v4). k is lane-parallel (no serial-k
// chain, v5's failure). 2 k-passes of 32 channels; phase 2 accumulates a2 across
// passes; sH = 15.4 KB. Phase 2 = v2's conflict-free broadcast GEMM (px = 2pg+16j).
__global__ __launch_bounds__(256, 4) void fused_stage(
    const float* __restrict__ in,    // [32,256,56,56]
    const float* __restrict__ gw,    // [4,64,4,3,3]  (i,k,cc,dy,dx)
    const float* __restrict__ gb,    // [256] flat (i*64+k)
    const float* __restrict__ bnag, const float* __restrict__ bnab,
    const float* __restrict__ bnam, const float* __restrict__ bnav,
    const float* __restrict__ pw,    // [256,64]
    const float* __restrict__ pb,    // [256]
    const float* __restrict__ bnbg, const float* __restrict__ bnbb,
    const float* __restrict__ bnbm, const float* __restrict__ bnbv,
    float* __restrict__ out)         // [32,256,56,56]
{
    __shared__ float sH[32 * SHS];   // 15360 B: 32 of 64 intermediate channels

    const int tid = threadIdx.x;

    // XCD-aware decode (v2's, bijective: 3584 % 8 == 0): the 4 g-blocks sharing one
    // (b,t) input tile are 8 apart -> same XCD L2.
    const int idx  = blockIdx.x;
    const int xcd  = idx & 7;
    const int qq   = idx >> 3;
    const int g    = qq & 3;
    const int slot = qq >> 2;        // 0..111
    const int u    = slot * 8 + xcd; // 0..895
    const int b    = u / 28;
    const int t    = u - b * 28;     // 2-row tile 0..27
    const int y0   = t * 2;

    const int l  = tid & 63;
    const int wv = tid >> 6;         // wave 0..3
    const int kq = l >> 3;           // 0..7 : channel within wave
    const int s  = l & 7;            // 0..7 : px slot; lane covers px [8s-4, 8s+4)

    // phase-2 ownership (constant across passes)
    const int og = tid >> 3;         // 0..31 -> out channels og*2, og*2+1
    const int pg = tid & 7;          // 0..7  -> px 2*pg + 16*j, j=0..6

    float a2[2][14];                 // accumulated across both k-passes
#pragma unroll
    for (int i = 0; i < 2; ++i)
#pragma unroll
        for (int xx = 0; xx < 14; ++xx) a2[i][xx] = 0.f;

#pragma unroll 1
    for (int pass = 0; pass < 2; ++pass) {
        // ---- phase 1: grouped 3x3 conv, channels k = pass*32 .. +31, lane-parallel ----
        const int kl = wv * 8 + kq;          // 0..31 (sH row)
        const int k  = pass * 32 + kl;
        const int c  = g * 64 + k;

        float acc[2][8];                     // 2 out rows x 8 px (px 8s-4+j)
#pragma unroll
        for (int r = 0; r < 2; ++r)
#pragma unroll
            for (int j = 0; j < 8; ++j) acc[r][j] = 0.f;

        const float* chp0 = in + ((size_t)(b * 256 + k * 4)) * HW;
        const float* wkp0 = gw + (size_t)c * 36;

#pragma unroll
        for (int cc = 0; cc < 4; ++cc) {
            float wr[9];
#pragma unroll
            for (int j = 0; j < 9; ++j) wr[j] = wkp0[cc * 9 + j];
            const float* chp = chp0 + cc * HW;
#pragma unroll
            for (int ry = 0; ry < 4; ++ry) {
                const int gy = y0 - 1 + ry;              // block-uniform
                float4 vA = make_float4(0.f, 0.f, 0.f, 0.f);
                float4 vB = vA;
                if ((unsigned)gy < 56u) {                // zero-pad rows (uniform branch)
                    const float* rp = chp + gy * 56;     // 16B-aligned (224B row)
                    if (s >= 1) vA = *(const float4*)(rp + 8 * s - 4);  // px 8s-4..8s-1
                    if (s <= 6) vB = *(const float4*)(rp + 8 * s);      // px 8s..8s+3
                }
                // halo: px 8s-5 from lane s-1 (vB.w), px 8s+4 from lane s+1 (vA.x).
                // Garbage at s==0 / s==7 feeds only never-stored outputs.
                const float L = __shfl_up(vB.w, 1);
                const float R = __shfl_down(vA.x, 1);
                const float win[10] = {L, vA.x, vA.y, vA.z, vA.w,
                                       vB.x, vB.y, vB.z, vB.w, R};  // px 8s-5 .. 8s+4
#pragma unroll
                for (int r = 0; r < 2; ++r) {
                    const int wi = ry - r;               // weight row
                    if (wi < 0 || wi > 2) continue;      // dead-code after unroll
                    const float w0 = wr[wi * 3 + 0];
                    const float w1 = wr[wi * 3 + 1];
                    const float w2 = wr[wi * 3 + 2];
#pragma unroll
                    for (int j = 0; j < 8; ++j)          // out px 8s-4+j
                        acc[r][j] = fmaf(w2, win[j + 2],
                                    fmaf(w1, win[j + 1],
                                    fmaf(w0, win[j], acc[r][j])));
                }
            }
        }

        // bias + BN-a + ReLU -> sH (float4 stores; 2-way bank alias on writes = free)
        {
            const float sc = bnag[c] * rsqrtf(bnav[c] + 1e-5f);
            const float sh = fmaf(gb[c], sc, bnab[c] - bnam[c] * sc);
#pragma unroll
            for (int r = 0; r < 2; ++r) {
                float* sp = &sH[kl * SHS + r * 56];
                if (s >= 1) {                            // px 8s-4..8s-1 valid
                    float4 v;
                    v.x = fmaxf(fmaf(acc[r][0], sc, sh), 0.f);
                    v.y = fmaxf(fmaf(acc[r][1], sc, sh), 0.f);
                    v.z = fmaxf(fmaf(acc[r][2], sc, sh), 0.f);
                    v.w = fmaxf(fmaf(acc[r][3], sc, sh), 0.f);
                    *(float4*)(sp + 8 * s - 4) = v;
                }
                if (s <= 6) {                            // px 8s..8s+3 valid
                    float4 v;
                    v.x = fmaxf(fmaf(acc[r][4], sc, sh), 0.f);
                    v.y = fmaxf(fmaf(acc[r][5], sc, sh), 0.f);
                    v.z = fmaxf(fmaf(acc[r][6], sc, sh), 0.f);
                    v.w = fmaxf(fmaf(acc[r][7], sc, sh), 0.f);
                    *(float4*)(sp + 8 * s) = v;
                }
            }
        }
        __syncthreads();

        // ---- phase 2: accumulate this pass's 32 channels into a2[2][14] ----
        const float* wp = pw + (size_t)(g * 64 + og * 2) * 64 + pass * 32;
        for (int c4 = 0; c4 < 32; c4 += 4) {
            const float4 w0 = *(const float4*)(wp + c4);        // L1-hot
            const float4 w1 = *(const float4*)(wp + 64 + c4);
            const float w0a[4] = {w0.x, w0.y, w0.z, w0.w};
            const float w1a[4] = {w1.x, w1.y, w1.z, w1.w};
#pragma unroll
            for (int q2 = 0; q2 < 4; ++q2) {
                const float* hrow = &sH[(c4 + q2) * SHS];
                const float wa = w0a[q2];
                const float wb = w1a[q2];
#pragma unroll
                for (int j = 0; j < 7; ++j) {
                    // 8 distinct addr x 8-way broadcast -> conflict-free
                    const float2 hv = *(const float2*)&hrow[2 * pg + 16 * j];
                    a2[0][2*j]   = fmaf(wa, hv.x, a2[0][2*j]);
                    a2[0][2*j+1] = fmaf(wa, hv.y, a2[0][2*j+1]);
                    a2[1][2*j]   = fmaf(wb, hv.x, a2[1][2*j]);
                    a2[1][2*j+1] = fmaf(wb, hv.y, a2[1][2*j+1]);
                }
            }
        }
        if (pass == 0) __syncthreads();   // protect sH before pass-1 overwrites it
    }

    // ---- bias + BN-b + ReLU -> global (8 lines/store-inst) ----
#pragma unroll
    for (int i = 0; i < 2; ++i) {
        const int o = g * 64 + og * 2 + i;
        const float sc = bnbg[o] * rsqrtf(bnbv[o] + 1e-5f);
        const float sh = fmaf(pb[o], sc, bnbb[o] - bnbm[o] * sc);
        float* op = out + ((size_t)(b * 256 + o)) * HW + y0 * 56;
#pragma unroll
        for (int j = 0; j < 7; ++j) {
            float v0 = fmaxf(fmaf(a2[i][2*j],   sc, sh), 0.f);
            float v1 = fmaxf(fmaf(a2[i][2*j+1], sc, sh), 0.f);
            *(float2*)(op + 2 * pg + 16 * j) = make_float2(v0, v1);
        }
    }
}

extern "C" void kernel_launch(void* const* d_in, const int* in_sizes, int n_in,
                              void* d_out, int out_size, void* d_ws, size_t ws_size,
                              hipStream_t stream) {
    const float* x     = (const float*)d_in[0];
    const float* w1    = (const float*)d_in[1];
    const float* b1    = (const float*)d_in[2];
    const float* bn1ag = (const float*)d_in[3];
    const float* bn1ab = (const float*)d_in[4];
    const float* bn1am = (const float*)d_in[5];
    const float* bn1av = (const float*)d_in[6];
    const float* pw1   = (const float*)d_in[7];
    const float* pb1   = (const float*)d_in[8];
    const float* bn1bg = (const float*)d_in[9];
    const float* bn1bb = (const float*)d_in[10];
    const float* bn1bm = (const float*)d_in[11];
    const float* bn1bv = (const float*)d_in[12];
    const float* w2    = (const float*)d_in[13];
    const float* b2    = (const float*)d_in[14];
    const float* bn2ag = (const float*)d_in[15];
    const float* bn2ab = (const float*)d_in[16];
    const float* bn2am = (const float*)d_in[17];
    const float* bn2av = (const float*)d_in[18];
    const float* pw2   = (const float*)d_in[19];
    const float* pb2   = (const float*)d_in[20];
    const float* bn2bg = (const float*)d_in[21];
    const float* bn2bb = (const float*)d_in[22];
    const float* bn2bm = (const float*)d_in[23];
    const float* bn2bv = (const float*)d_in[24];

    float* mid  = (float*)d_ws;      // 32*256*56*56*4 = 102,760,448 B
    float* outp = (float*)d_out;

    const int grid = 32 * 4 * 28;    // (b, g, 2-row tile) via XCD-aware decode

    fused_stage<<<grid, 256, 0, stream>>>(x,   w1, b1, bn1ag, bn1ab, bn1am, bn1av,
                                          pw1, pb1, bn1bg, bn1bb, bn1bm, bn1bv, mid);
    fused_stage<<<grid, 256, 0, stream>>>(mid, w2, b2, bn2ag, bn2ab, bn2am, bn2av,
                                          pw2, pb2, bn2bg, bn2bb, bn2bm, bn2bv, outp);
}

// Round 9
// 417.443 us; speedup vs baseline: 3.2915x; 3.2915x over previous
//
#include <hip/hip_runtime.h>

#define HW 3136      // 56*56
#define SHS 232      // sH row stride: 224 px + 8 pad (v0-proven: 0 measured conflicts)

// Fused residual-stage: grouped3x3 conv + bias + BN + ReLU -> (LDS) -> grouped1x1 conv
// + bias + BN + ReLU -> global.
// v7 = v0 (174us, no spill) + three surgical edits:
//  (1) halo px via 2 shfl+cndmask per (cc,ry) instead of 2 scalar loads (~-30% TA line-req)
//  (2) XCD-aware block decode (v2-proven: FETCH 309->113 MB)
//  (3) pw read from global L1 (v5-proven path), sW staging dropped.
// All array writes unconditional / ternary-scalar only (v3/v6 spill lesson).
__global__ __launch_bounds__(256, 2) void fused_stage(
    const float* __restrict__ in,    // [32,256,56,56]
    const float* __restrict__ gw,    // [4,64,4,3,3]  (i,k,cc,dy,dx)
    const float* __restrict__ gb,    // [256] flat (i*64+k)
    const float* __restrict__ bnag, const float* __restrict__ bnab,
    const float* __restrict__ bnam, const float* __restrict__ bnav,
    const float* __restrict__ pw,    // [256,64]
    const float* __restrict__ pb,    // [256]
    const float* __restrict__ bnbg, const float* __restrict__ bnbb,
    const float* __restrict__ bnbm, const float* __restrict__ bnbv,
    float* __restrict__ out)         // [32,256,56,56]
{
    __shared__ float sH[64 * SHS];   // 59392 B: intermediate h[k][r*56+x]

    const int tid = threadIdx.x;

    // XCD-aware decode (bijective: grid 1792 = 8*224): the 4 g-blocks sharing one
    // (b,t) input tile are 8 apart -> same XCD, adjacent in time -> L2 hits.
    const int idx  = blockIdx.x;
    const int xcd  = idx & 7;
    const int qq   = idx >> 3;       // 0..223
    const int g    = qq & 3;
    const int slot = qq >> 2;        // 0..55
    const int u    = slot * 8 + xcd; // 0..447
    const int b    = u / 14;
    const int t    = u - b * 14;     // 4-row tile 0..13
    const int y0   = t * 4;

    // ---- phase 1: grouped 3x3 conv for conv-index g, all 64 groups k ----
    const int k  = tid >> 2;         // 0..63 group (intermediate channel g*64+k)
    const int xs = tid & 3;          // x-strip of 14
    const int x0 = xs * 14;

    float wr[36];                    // gw[g][k][cc][dy][dx], contiguous, 16B-aligned
    {
        const float4* w4 = (const float4*)(gw + (size_t)(g * 64 + k) * 36);
#pragma unroll
        for (int j = 0; j < 9; ++j) {
            float4 v = w4[j];
            wr[4*j+0] = v.x; wr[4*j+1] = v.y; wr[4*j+2] = v.z; wr[4*j+3] = v.w;
        }
    }

    float acc[4][14];
#pragma unroll
    for (int r = 0; r < 4; ++r)
#pragma unroll
        for (int xx = 0; xx < 14; ++xx) acc[r][xx] = 0.f;

#pragma unroll
    for (int cc = 0; cc < 4; ++cc) {
        const float* chp = in + ((size_t)(b * 256 + k * 4 + cc)) * HW;
#pragma unroll
        for (int ry = 0; ry < 6; ++ry) {
            const int gy = y0 - 1 + ry;          // block-uniform after unroll
            if ((unsigned)gy >= 56u) continue;   // zero-pad rows (uniform branch)
            const float* rp = chp + gy * 56;
            float rr[16];                        // cols x0-1 .. x0+14
#pragma unroll
            for (int j = 0; j < 7; ++j) {
                float2 v = *(const float2*)(rp + x0 + 2 * j);  // 8B-aligned
                rr[1 + 2*j] = v.x; rr[2 + 2*j] = v.y;
            }
            // halo from neighbor lanes (lane = k*4+xs; xs+-1 adjacent in wave).
            // Uniform branch -> shfl safe. Scalar ternary masks (no array-under-branch).
            const float left  = __shfl_up(rr[14], 1);   // lane-1's px x0-1
            const float right = __shfl_down(rr[1], 1);  // lane+1's px x0+14
            rr[0]  = (xs == 0) ? 0.f : left;
            rr[15] = (xs == 3) ? 0.f : right;
            const int rlo = (ry >= 2) ? ry - 2 : 0;
            const int rhi = (ry <= 3) ? ry : 3;
#pragma unroll
            for (int r = 0; r < 4; ++r) {
                if (r < rlo || r > rhi) continue;  // dead-code after unroll
                const int dy = ry - r;
                const float w0 = wr[cc*9 + dy*3 + 0];
                const float w1 = wr[cc*9 + dy*3 + 1];
                const float w2 = wr[cc*9 + dy*3 + 2];
#pragma unroll
                for (int xx = 0; xx < 14; ++xx)
                    acc[r][xx] = fmaf(w2, rr[xx+2],
                                 fmaf(w1, rr[xx+1],
                                 fmaf(w0, rr[xx], acc[r][xx])));
            }
        }
    }

    // bias + BN-a + ReLU -> sH
    {
        const int c = g * 64 + k;
        const float sc = bnag[c] * rsqrtf(bnav[c] + 1e-5f);
        const float sh = fmaf(gb[c], sc, bnab[c] - bnam[c] * sc);
#pragma unroll
        for (int r = 0; r < 4; ++r)
#pragma unroll
            for (int j = 0; j < 7; ++j) {
                float v0 = fmaxf(fmaf(acc[r][2*j],   sc, sh), 0.f);
                float v1 = fmaxf(fmaf(acc[r][2*j+1], sc, sh), 0.f);
                *(float2*)&sH[k * SHS + r * 56 + x0 + 2*j] = make_float2(v0, v1);
            }
    }
    __syncthreads();

    // ---- phase 2: 64x224 = W[64x64] * sH[64x224] GEMM, 4-out x 14-px tile ----
    const int og = tid >> 4;         // 0..15 -> out channels og*4..og*4+3
    const int pg = tid & 15;         // 0..15 -> px p0..p0+13
    const int p0 = pg * 14;

    float a2[4][14];
#pragma unroll
    for (int i = 0; i < 4; ++i)
#pragma unroll
        for (int xx = 0; xx < 14; ++xx) a2[i][xx] = 0.f;

    const float* wp = pw + (size_t)(g * 64 + og * 4) * 64;  // 4 rows, stride 64

    for (int c4 = 0; c4 < 64; c4 += 4) {
        const float4 wv0 = *(const float4*)(wp + 0 * 64 + c4);  // L1-resident
        const float4 wv1 = *(const float4*)(wp + 1 * 64 + c4);
        const float4 wv2 = *(const float4*)(wp + 2 * 64 + c4);
        const float4 wv3 = *(const float4*)(wp + 3 * 64 + c4);
        const float w0a[4] = {wv0.x, wv0.y, wv0.z, wv0.w};
        const float w1a[4] = {wv1.x, wv1.y, wv1.z, wv1.w};
        const float w2a[4] = {wv2.x, wv2.y, wv2.z, wv2.w};
        const float w3a[4] = {wv3.x, wv3.y, wv3.z, wv3.w};
#pragma unroll
        for (int q2 = 0; q2 < 4; ++q2) {
            const float* hrow = &sH[(c4 + q2) * SHS + p0];
            float hr[14];
#pragma unroll
            for (int j = 0; j < 7; ++j) {
                float2 v = *(const float2*)&hrow[2*j];   // 16 addr-pairs, conflict-free
                hr[2*j] = v.x; hr[2*j+1] = v.y;
            }
            const float wa = w0a[q2], wb = w1a[q2], wc = w2a[q2], wd = w3a[q2];
#pragma unroll
            for (int xx = 0; xx < 14; ++xx) {
                a2[0][xx] = fmaf(wa, hr[xx], a2[0][xx]);
                a2[1][xx] = fmaf(wb, hr[xx], a2[1][xx]);
                a2[2][xx] = fmaf(wc, hr[xx], a2[2][xx]);
                a2[3][xx] = fmaf(wd, hr[xx], a2[3][xx]);
            }
        }
    }

    // bias + BN-b + ReLU -> global
#pragma unroll
    for (int i = 0; i < 4; ++i) {
        const int o = g * 64 + og * 4 + i;
        const float sc = bnbg[o] * rsqrtf(bnbv[o] + 1e-5f);
        const float sh = fmaf(pb[o], sc, bnbb[o] - bnbm[o] * sc);
        float* op = out + ((size_t)(b * 256 + o)) * HW + y0 * 56 + p0;
#pragma unroll
        for (int j = 0; j < 7; ++j) {
            float v0 = fmaxf(fmaf(a2[i][2*j],   sc, sh), 0.f);
            float v1 = fmaxf(fmaf(a2[i][2*j+1], sc, sh), 0.f);
            *(float2*)(op + 2*j) = make_float2(v0, v1);
        }
    }
}

extern "C" void kernel_launch(void* const* d_in, const int* in_sizes, int n_in,
                              void* d_out, int out_size, void* d_ws, size_t ws_size,
                              hipStream_t stream) {
    const float* x     = (const float*)d_in[0];
    const float* w1    = (const float*)d_in[1];
    const float* b1    = (const float*)d_in[2];
    const float* bn1ag = (const float*)d_in[3];
    const float* bn1ab = (const float*)d_in[4];
    const float* bn1am = (const float*)d_in[5];
    const float* bn1av = (const float*)d_in[6];
    const float* pw1   = (const float*)d_in[7];
    const float* pb1   = (const float*)d_in[8];
    const float* bn1bg = (const float*)d_in[9];
    const float* bn1bb = (const float*)d_in[10];
    const float* bn1bm = (const float*)d_in[11];
    const float* bn1bv = (const float*)d_in[12];
    const float* w2    = (const float*)d_in[13];
    const float* b2    = (const float*)d_in[14];
    const float* bn2ag = (const float*)d_in[15];
    const float* bn2ab = (const float*)d_in[16];
    const float* bn2am = (const float*)d_in[17];
    const float* bn2av = (const float*)d_in[18];
    const float* pw2   = (const float*)d_in[19];
    const float* pb2   = (const float*)d_in[20];
    const float* bn2bg = (const float*)d_in[21];
    const float* bn2bb = (const float*)d_in[22];
    const float* bn2bm = (const float*)d_in[23];
    const float* bn2bv = (const float*)d_in[24];

    float* mid  = (float*)d_ws;      // 32*256*56*56*4 = 102,760,448 B
    float* outp = (float*)d_out;

    const int grid = 32 * 4 * 14;    // (b, g, 4-row tile) via XCD-aware decode

    fused_stage<<<grid, 256, 0, stream>>>(x,   w1, b1, bn1ag, bn1ab, bn1am, bn1av,
                                          pw1, pb1, bn1bg, bn1bb, bn1bm, bn1bv, mid);
    fused_stage<<<grid, 256, 0, stream>>>(mid, w2, b2, bn2ag, bn2ab, bn2am, bn2av,
                                          pw2, pb2, bn2bg, bn2bb, bn2bm, bn2bv, outp);
}